// Round 2
// baseline (410.343 us; speedup 1.0000x reference)
//
#include <hip/hip_runtime.h>

#define B_ 256
#define M_ 512
#define N_ 256
#define K_ 16
#define RB 64          // rows per pass-1 block
#define NCH 16         // number of 16-col chunks (256/16)

// swizzled byte offset inside a 4 KiB x-tile: row r (0..63), c4 (0..3 float4 col)
__device__ __forceinline__ int sbyte(int r, int c4) {
    return ((r << 6) + (c4 << 4)) ^ ((r & 7) << 4);
}

// ---------------- Pass 1 ----------------
// grid = B_ * (M_/RB) = 2048 blocks, 256 threads.
// Thread (row = t&63, ksub = t>>6) computes xv[b,m,ksub*4..+4) and a share of l.
__global__ __launch_bounds__(256, 6) void fm_pass1(
    const float* __restrict__ x, const float* __restrict__ w,
    const float* __restrict__ bias, const float* __restrict__ v,
    float* __restrict__ xv, float* __restrict__ svpart, float* __restrict__ out)
{
    __shared__ __align__(16) float vL[N_][K_];           // 16 KiB
    __shared__ __align__(16) float wL[N_];               // 1 KiB
    __shared__ __align__(16) unsigned char xT[2][RB * 16 * 4]; // 2 x 4 KiB, swizzled

    const int t    = threadIdx.x;
    const int ksub = t >> 6;          // 0..3  (wave index)
    const int row  = t & 63;          // 0..63
    const int blk  = blockIdx.x;
    const int b    = blk >> 3;        // 8 row-chunks per batch
    const int m0   = (blk & 7) * RB;

    // stage v (4096 floats) and w (256 floats)
    {
        const float4* v4 = (const float4*)v;
        float4* vL4 = (float4*)&vL[0][0];
        #pragma unroll
        for (int i = 0; i < 4; ++i) vL4[t + 256 * i] = v4[t + 256 * i];
        wL[t] = w[t];
    }

    const float* xb = x + ((size_t)b * M_ + m0) * N_;
    // staging: lane t loads float4 of row lr, float4-col lc4 of each chunk
    const int lr = t >> 2, lc4 = t & 3;
    const float* gbase = xb + (size_t)lr * N_ + lc4 * 4;
    unsigned char* const wdst0 = &xT[0][0] + sbyte(lr, lc4);
    unsigned char* const wdst1 = &xT[1][0] + sbyte(lr, lc4);

    float acc0 = 0.f, acc1 = 0.f, acc2 = 0.f, acc3 = 0.f, lacc = 0.f;

    // prologue: chunk0 -> xT[0], prefetch chunk1
    float4 st = *(const float4*)(gbase + 0 * 16);
    *(float4*)wdst0 = st;
    st = *(const float4*)(gbase + 1 * 16);
    __syncthreads();

    for (int c = 0; c < NCH; ++c) {
        if (c + 1 < NCH) {
            *(float4*)((((c + 1) & 1) ? wdst1 : wdst0)) = st;   // chunk c+1
            if (c + 2 < NCH) st = *(const float4*)(gbase + (c + 2) * 16);
        }
        const unsigned char* xr = &xT[c & 1][0];
        const bool dol = ((c >> 2) == ksub);    // this wave's share of the linear term
        #pragma unroll
        for (int c4 = 0; c4 < 4; ++c4) {
            const float4 xq = *(const float4*)(xr + sbyte(row, c4));
            #pragma unroll
            for (int j = 0; j < 4; ++j) {
                const int n = c * 16 + c4 * 4 + j;
                const float xs = (j == 0) ? xq.x : (j == 1) ? xq.y : (j == 2) ? xq.z : xq.w;
                const float4 vv = *(const float4*)&vL[n][ksub * 4];
                acc0 += xs * vv.x; acc1 += xs * vv.y; acc2 += xs * vv.z; acc3 += xs * vv.w;
                if (dol) lacc += xs * wL[n];
            }
        }
        __syncthreads();
    }

    // write xv slice (16B contiguous per thread)
    {
        float4* xvp = (float4*)(xv + ((size_t)b * M_ + m0 + row) * K_ + ksub * 4);
        *xvp = float4{acc0, acc1, acc2, acc3};
    }

    // per-wave butterfly reduce over the 64 rows -> svpart[blk][ksub*4..+4)
    float s0 = acc0, s1 = acc1, s2 = acc2, s3 = acc3;
    #pragma unroll
    for (int off = 1; off < 64; off <<= 1) {
        s0 += __shfl_xor(s0, off);
        s1 += __shfl_xor(s1, off);
        s2 += __shfl_xor(s2, off);
        s3 += __shfl_xor(s3, off);
    }
    if (row == 0)
        *(float4*)(svpart + (size_t)blk * 16 + ksub * 4) = float4{s0, s1, s2, s3};

    // combine the 4 ksub partial linear sums per row; write l (+bias) to out
    float* lred = (float*)&xT[0][0];    // reuse tile (loop-end barrier protects it)
    lred[ksub * 64 + row] = lacc;
    __syncthreads();
    if (t < 64)
        out[(size_t)b * M_ + m0 + t] =
            lred[t] + lred[64 + t] + lred[128 + t] + lred[192 + t] + bias[0];
}

// ---------------- Pass 2 ----------------
// grid = B_*2 blocks, 256 threads; thread per row.
__global__ __launch_bounds__(256) void fm_pass2(
    const float* __restrict__ xv, const float* __restrict__ svpart,
    float* __restrict__ out)
{
    const int t = threadIdx.x;
    const int blk = blockIdx.x;
    const int b = blk >> 1;
    const int m = (blk & 1) * 256 + t;
    __shared__ __align__(16) float svL[16];
    if (t < 16) {
        float s = 0.f;
        #pragma unroll
        for (int p = 0; p < 8; ++p) s += svpart[((size_t)b * 8 + p) * 16 + t];
        svL[t] = s;
    }
    __syncthreads();

    const float4* xvp = (const float4*)(xv + ((size_t)b * M_ + m) * K_);
    float4 a0 = xvp[0], a1 = xvp[1], a2 = xvp[2], a3 = xvp[3];
    const float4* s4 = (const float4*)svL;
    float4 s0 = s4[0], s1 = s4[1], s2 = s4[2], s3 = s4[3];

    float rs = a0.x * s0.x + a0.y * s0.y + a0.z * s0.z + a0.w * s0.w
             + a1.x * s1.x + a1.y * s1.y + a1.z * s1.z + a1.w * s1.w
             + a2.x * s2.x + a2.y * s2.y + a2.z * s2.z + a2.w * s2.w
             + a3.x * s3.x + a3.y * s3.y + a3.z * s3.z + a3.w * s3.w;
    float dg = a0.x * a0.x + a0.y * a0.y + a0.z * a0.z + a0.w * a0.w
             + a1.x * a1.x + a1.y * a1.y + a1.z * a1.z + a1.w * a1.w
             + a2.x * a2.x + a2.y * a2.y + a2.z * a2.z + a2.w * a2.w
             + a3.x * a3.x + a3.y * a3.y + a3.z * a3.z + a3.w * a3.w;

    const size_t o = (size_t)b * M_ + m;
    out[o] = out[o] + 0.5f * (rs - dg);
}

extern "C" void kernel_launch(void* const* d_in, const int* in_sizes, int n_in,
                              void* d_out, int out_size, void* d_ws, size_t ws_size,
                              hipStream_t stream) {
    const float* x    = (const float*)d_in[0];
    const float* w    = (const float*)d_in[1];
    const float* bias = (const float*)d_in[2];
    const float* v    = (const float*)d_in[3];
    float* out = (float*)d_out;

    float* xv     = (float*)d_ws;                 // B*M*K floats = 8 MiB
    float* svpart = xv + (size_t)B_ * M_ * K_;    // 2048*16 floats = 128 KiB

    fm_pass1<<<dim3(B_ * (M_ / RB)), dim3(256), 0, stream>>>(x, w, bias, v, xv, svpart, out);
    fm_pass2<<<dim3(B_ * 2), dim3(256), 0, stream>>>(xv, svpart, out);
}